// Round 2
// baseline (1562.301 us; speedup 1.0000x reference)
//
#include <hip/hip_runtime.h>
#include <math.h>

// ---------------------------------------------------------------------------
// GCN 3-layer forward. Round 1: bf16-packed feature gather.
// GEMM outputs are packed bf162 (2 feats/dword) so the aggregation gathers
// 256 B/row (128-f) or 80 B/row (40-f) instead of 512/160 B fp32.
// Aggregation: wave-per-node, 8-edge unrolled prefetch, 256-thr blocks,
// grid 2048 -> full occupancy. h (post-agg) stays fp32 for GEMM input.
// ---------------------------------------------------------------------------

__device__ __forceinline__ float2 bf2_unpack(unsigned u) {
    float2 r;
    r.x = __uint_as_float(u << 16);
    r.y = __uint_as_float(u & 0xffff0000u);
    return r;
}
__device__ __forceinline__ unsigned bf2_pack(float a, float b) {
    unsigned ua = __float_as_uint(a);
    unsigned ub = __float_as_uint(b);
    ua = (ua + 0x7fffu + ((ua >> 16) & 1u)) >> 16;
    ub = (ub + 0x7fffu + ((ub >> 16) & 1u)) >> 16;
    return ua | (ub << 16);
}

// ---------- edge-index dtype detection (int32 vs int64 layout) ----------
__global__ void k_detect(const unsigned* __restrict__ raw, int nsample, int* __restrict__ flag) {
    int i = blockIdx.x * blockDim.x + threadIdx.x;
    if (i < nsample) {
        if (raw[2 * i + 1] != 0u) atomicOr(flag, 1);
    }
}

__device__ __forceinline__ int edge_src(const unsigned* raw, int e, int E, int is64) {
    return is64 ? (int)raw[2 * (size_t)e] : (int)raw[e];
}
__device__ __forceinline__ int edge_dst(const unsigned* raw, int e, int E, int is64) {
    return is64 ? (int)raw[2 * ((size_t)E + e)] : (int)raw[(size_t)E + e];
}

// ---------- degree + per-dst edge counts ----------
__global__ void k_deg(const unsigned* __restrict__ raw, const float* __restrict__ ew,
                      float* __restrict__ degw, int* __restrict__ counts,
                      const int* __restrict__ flag, int E) {
    int e = blockIdx.x * blockDim.x + threadIdx.x;
    if (e >= E) return;
    int is64 = (*flag == 0);
    int d = edge_dst(raw, e, E, is64);
    atomicAdd(&degw[d], ew[e]);
    atomicAdd(&counts[d], 1);
}

// ---------- hierarchical exclusive scan over counts (N <= 131072) ----------
__global__ void k_scan_a(int* __restrict__ data, int* __restrict__ bsums, int N) {
    __shared__ int s[512];
    int tid = threadIdx.x;
    int i = blockIdx.x * 512 + tid;
    int v = (i < N) ? data[i] : 0;
    s[tid] = v;
    __syncthreads();
    for (int off = 1; off < 512; off <<= 1) {
        int t = (tid >= off) ? s[tid - off] : 0;
        __syncthreads();
        if (tid >= off) s[tid] += t;
        __syncthreads();
    }
    if (tid == 511) bsums[blockIdx.x] = s[511];
    if (i < N) data[i] = s[tid] - v;
}

__global__ void k_scan_b(int* __restrict__ bsums, int NB) {
    __shared__ int s[256];
    int tid = threadIdx.x;
    int v = (tid < NB) ? bsums[tid] : 0;
    s[tid] = v;
    __syncthreads();
    for (int off = 1; off < 256; off <<= 1) {
        int t = (tid >= off) ? s[tid - off] : 0;
        __syncthreads();
        if (tid >= off) s[tid] += t;
        __syncthreads();
    }
    if (tid < NB) bsums[tid] = s[tid] - v;
}

__global__ void k_scan_c(const int* __restrict__ data, const int* __restrict__ bsums,
                         int* __restrict__ rowptr, int* __restrict__ fill,
                         const float* __restrict__ degw, float* __restrict__ dinv,
                         int N, int E) {
    int i = blockIdx.x * 512 + threadIdx.x;
    if (i < N) {
        int v = data[i] + bsums[blockIdx.x];
        rowptr[i] = v;
        fill[i] = v;
        dinv[i] = rsqrtf(degw[i] + 1.0f);
    }
    if (blockIdx.x == 0 && threadIdx.x == 0) rowptr[N] = E;
}

// ---------- scatter edges into CSR slots with precomputed coefficient ----------
__global__ void k_scatter(const unsigned* __restrict__ raw, const float* __restrict__ ew,
                          const float* __restrict__ dinv, int* __restrict__ fill,
                          int* __restrict__ srcs, float* __restrict__ coefs,
                          const int* __restrict__ flag, int E) {
    int e = blockIdx.x * blockDim.x + threadIdx.x;
    if (e >= E) return;
    int is64 = (*flag == 0);
    int s = edge_src(raw, e, E, is64);
    int d = edge_dst(raw, e, E, is64);
    float c = dinv[s] * ew[e] * dinv[d];
    int p = atomicAdd(&fill[d], 1);
    srcs[p] = s;
    coefs[p] = c;
}

// ---------- fp32 GEMM: Yp = pack_bf162( act(X)[N,128] @ W[128,DOUT] ) ----------
// Lane owns columns 2*lane, 2*lane+1 (lane < DOUT/2). BN=true applies
// y = relu(x*scale+shift) while staging X into LDS.
template <int DOUT, int KC, bool BN>
__global__ __launch_bounds__(256) void k_gemm(
    const float* __restrict__ X, const float* __restrict__ W,
    const float* __restrict__ scale, const float* __restrict__ shift,
    unsigned* __restrict__ Y, int N)
{
    constexpr int NCH = 128 / KC;
    constexpr int NDW = DOUT / 2;  // packed dwords per output row
    __shared__ __align__(16) float Wl[KC * DOUT];
    __shared__ __align__(16) float Xs[4][8 * 128];
    __shared__ float sc_l[128], sh_l[128];

    const int tid = threadIdx.x;
    const int wave = tid >> 6, lane = tid & 63;
    if (BN) {
        if (tid < 128) { sc_l[tid] = scale[tid]; sh_l[tid] = shift[tid]; }
    }
    __syncthreads();

    const int srow = lane >> 3;
    const int skk = (lane & 7) * 16;

    for (int base = blockIdx.x * 32; base < N; base += gridDim.x * 32) {
        {
            int r = base + wave * 8 + srow;
            float4 v[4];
            if (r < N) {
                const float4* p = (const float4*)(X + (size_t)r * 128 + skk);
                v[0] = p[0]; v[1] = p[1]; v[2] = p[2]; v[3] = p[3];
            } else {
                v[0] = v[1] = v[2] = v[3] = make_float4(0.f, 0.f, 0.f, 0.f);
            }
            if (BN) {
                float* vf = (float*)v;
#pragma unroll
                for (int j = 0; j < 16; j++)
                    vf[j] = fmaxf(vf[j] * sc_l[skk + j] + sh_l[skk + j], 0.f);
            }
            float4* q = (float4*)&Xs[wave][srow * 128 + skk];
            q[0] = v[0]; q[1] = v[1]; q[2] = v[2]; q[3] = v[3];
        }

        float acc0[8], acc1[8];
#pragma unroll
        for (int r = 0; r < 8; r++) { acc0[r] = 0.f; acc1[r] = 0.f; }

        for (int ch = 0; ch < NCH; ++ch) {
            __syncthreads();
            for (int idx = tid; idx < KC * DOUT / 4; idx += 256)
                ((float4*)Wl)[idx] = ((const float4*)(W + (size_t)ch * KC * DOUT))[idx];
            __syncthreads();

            for (int k = 0; k < KC; k += 4) {
                float4 a[8];
#pragma unroll
                for (int r = 0; r < 8; r++)
                    a[r] = *(const float4*)&Xs[wave][r * 128 + ch * KC + k];
#pragma unroll
                for (int kk = 0; kk < 4; kk++) {
                    float2 wv = make_float2(0.f, 0.f);
                    if (lane < NDW)
                        wv = *(const float2*)&Wl[(k + kk) * DOUT + 2 * lane];
#pragma unroll
                    for (int r = 0; r < 8; r++) {
                        float av = ((const float*)&a[r])[kk];
                        acc0[r] += av * wv.x;
                        acc1[r] += av * wv.y;
                    }
                }
            }
        }

#pragma unroll
        for (int r = 0; r < 8; r++) {
            int row = base + wave * 8 + r;
            if (row < N && lane < NDW)
                Y[(size_t)row * NDW + lane] = bf2_pack(acc0[r], acc1[r]);
        }
    }
}

// ---------- aggregation (128-wide, bf16 gather) + bias + BN partial sums ----------
__global__ __launch_bounds__(256) void k_agg128(
    const unsigned* __restrict__ xw, const int* __restrict__ rowptr,
    const int* __restrict__ srcs, const float* __restrict__ coefs,
    const float* __restrict__ dinv, const float* __restrict__ bias,
    float* __restrict__ h, float* __restrict__ bn_sum, float* __restrict__ bn_sq,
    int N)
{
    const int lane = threadIdx.x & 63;
    const int w = blockIdx.x * (blockDim.x >> 6) + (threadIdx.x >> 6);
    const int NW = gridDim.x * (blockDim.x >> 6);
    const float b0 = bias[2 * lane], b1 = bias[2 * lane + 1];
    float s0 = 0.f, s1 = 0.f, q0 = 0.f, q1 = 0.f;

    for (int i = w; i < N; i += NW) {
        const int rs = rowptr[i], re = rowptr[i + 1];
        const float di = dinv[i];
        float2 sv = bf2_unpack(xw[(size_t)i * 64 + lane]);
        float acc0 = di * di * sv.x, acc1 = di * di * sv.y;
        int j = rs;
        for (; j + 8 <= re; j += 8) {
            int ss[8]; float cc[8]; unsigned vv[8];
#pragma unroll
            for (int t = 0; t < 8; t++) { ss[t] = srcs[j + t]; cc[t] = coefs[j + t]; }
#pragma unroll
            for (int t = 0; t < 8; t++) vv[t] = xw[(size_t)ss[t] * 64 + lane];
#pragma unroll
            for (int t = 0; t < 8; t++) {
                float2 f = bf2_unpack(vv[t]);
                acc0 += cc[t] * f.x;
                acc1 += cc[t] * f.y;
            }
        }
        for (; j < re; j++) {
            float c = coefs[j];
            float2 f = bf2_unpack(xw[(size_t)srcs[j] * 64 + lane]);
            acc0 += c * f.x;
            acc1 += c * f.y;
        }
        acc0 += b0; acc1 += b1;
        *(float2*)&h[(size_t)i * 128 + 2 * lane] = make_float2(acc0, acc1);
        s0 += acc0; s1 += acc1; q0 += acc0 * acc0; q1 += acc1 * acc1;
    }
    atomicAdd(&bn_sum[2 * lane], s0);
    atomicAdd(&bn_sum[2 * lane + 1], s1);
    atomicAdd(&bn_sq[2 * lane], q0);
    atomicAdd(&bn_sq[2 * lane + 1], q1);
}

// ---------- BN finalize ----------
__global__ void k_bnfin(const float* __restrict__ bn_sum, const float* __restrict__ bn_sq,
                        const float* __restrict__ gamma, const float* __restrict__ beta,
                        float* __restrict__ scale, float* __restrict__ shift, int N) {
    int f = threadIdx.x;
    float inv = 1.0f / (float)N;
    float m = bn_sum[f] * inv;
    float v = bn_sq[f] * inv - m * m;
    float sc = gamma[f] * rsqrtf(v + 1e-5f);
    scale[f] = sc;
    shift[f] = beta[f] - m * sc;
}

// ---------- aggregation (40-wide, bf16 gather) + bias + log_softmax ----------
__global__ __launch_bounds__(256) void k_agg40(
    const unsigned* __restrict__ xw, const int* __restrict__ rowptr,
    const int* __restrict__ srcs, const float* __restrict__ coefs,
    const float* __restrict__ dinv, const float* __restrict__ bias,
    float* __restrict__ out, int N)
{
    const int lane = threadIdx.x & 63;
    const int w = blockIdx.x * (blockDim.x >> 6) + (threadIdx.x >> 6);
    const int NW = gridDim.x * (blockDim.x >> 6);
    const bool act = lane < 20;
    const float b0 = act ? bias[2 * lane] : 0.f;
    const float b1 = act ? bias[2 * lane + 1] : 0.f;

    for (int i = w; i < N; i += NW) {
        const int rs = rowptr[i], re = rowptr[i + 1];
        const float di = dinv[i];
        float acc0 = 0.f, acc1 = 0.f;
        if (act) {
            float2 sv = bf2_unpack(xw[(size_t)i * 20 + lane]);
            acc0 = di * di * sv.x;
            acc1 = di * di * sv.y;
        }
        int j = rs;
        for (; j + 8 <= re; j += 8) {
            int ss[8]; float cc[8]; unsigned vv[8];
#pragma unroll
            for (int t = 0; t < 8; t++) { ss[t] = srcs[j + t]; cc[t] = coefs[j + t]; }
#pragma unroll
            for (int t = 0; t < 8; t++) vv[t] = act ? xw[(size_t)ss[t] * 20 + lane] : 0u;
#pragma unroll
            for (int t = 0; t < 8; t++) {
                float2 f = bf2_unpack(vv[t]);
                acc0 += cc[t] * f.x;
                acc1 += cc[t] * f.y;
            }
        }
        for (; j < re; j++) {
            float c = coefs[j];
            unsigned v = act ? xw[(size_t)srcs[j] * 20 + lane] : 0u;
            float2 f = bf2_unpack(v);
            acc0 += c * f.x;
            acc1 += c * f.y;
        }
        acc0 += b0; acc1 += b1;

        float m = act ? fmaxf(acc0, acc1) : -1e30f;
#pragma unroll
        for (int off = 32; off; off >>= 1) m = fmaxf(m, __shfl_xor(m, off));
        float ex = act ? (expf(acc0 - m) + expf(acc1 - m)) : 0.f;
#pragma unroll
        for (int off = 32; off; off >>= 1) ex += __shfl_xor(ex, off);
        float ls = logf(ex);
        if (act)
            *(float2*)&out[(size_t)i * 40 + 2 * lane] = make_float2(acc0 - m - ls, acc1 - m - ls);
    }
}

// ---------------------------------------------------------------------------
extern "C" void kernel_launch(void* const* d_in, const int* in_sizes, int n_in,
                              void* d_out, int out_size, void* d_ws, size_t ws_size,
                              hipStream_t stream) {
    const float* x   = (const float*)d_in[0];
    const unsigned* ei = (const unsigned*)d_in[1];
    const float* ew  = (const float*)d_in[2];
    const float* W0  = (const float*)d_in[3];
    const float* b0  = (const float*)d_in[4];
    const float* g0  = (const float*)d_in[5];
    const float* be0 = (const float*)d_in[6];
    const float* W1  = (const float*)d_in[7];
    const float* b1  = (const float*)d_in[8];
    const float* g1  = (const float*)d_in[9];
    const float* be1 = (const float*)d_in[10];
    const float* W2  = (const float*)d_in[11];
    const float* b2  = (const float*)d_in[12];

    const int N = in_sizes[0] / 128;
    const int E = in_sizes[2];
    if (N <= 0 || E <= 0) return;

    char* ws = (char*)d_ws;
    size_t off = 0;
    auto carve = [&](size_t bytes) {
        char* p = ws + off;
        off += (bytes + 511) & ~((size_t)511);
        return p;
    };
    float*    F      = (float*)carve((size_t)N * 128 * 4);    // fp32 h buffer
    unsigned* P      = (unsigned*)carve((size_t)N * 64 * 4);  // packed bf162 xw
    int*      srcs   = (int*)carve((size_t)E * 4);
    float*    coefs  = (float*)carve((size_t)E * 4);
    int*      rowptr = (int*)carve((size_t)(N + 1) * 4);
    int*      fill   = (int*)carve((size_t)N * 4);
    int*      counts = (int*)carve((size_t)N * 4);
    float*    degw   = (float*)carve((size_t)N * 4);
    float*    dinv   = (float*)carve((size_t)N * 4);
    int*      bsums  = (int*)carve(1024 * 4);
    float*    bn     = (float*)carve(512 * 4);
    int*      flag   = (int*)carve(64);

    hipMemsetAsync(degw, 0, (size_t)N * 4, stream);
    hipMemsetAsync(counts, 0, (size_t)N * 4, stream);
    hipMemsetAsync(flag, 0, 4, stream);

    int nsample = E < 4096 ? E : 4096;
    k_detect<<<(nsample + 255) / 256, 256, 0, stream>>>(ei, nsample, flag);
    k_deg<<<(E + 255) / 256, 256, 0, stream>>>(ei, ew, degw, counts, flag, E);
    const int NB = (N + 511) / 512;
    k_scan_a<<<NB, 512, 0, stream>>>(counts, bsums, N);
    k_scan_b<<<1, 256, 0, stream>>>(bsums, NB);
    k_scan_c<<<NB, 512, 0, stream>>>(counts, bsums, rowptr, fill, degw, dinv, N, E);
    k_scatter<<<(E + 255) / 256, 256, 0, stream>>>(ei, ew, dinv, fill, srcs, coefs, flag, E);

    const int gemm_grid = 768;
    const int agg_grid = 2048;

    // ---- layer 0 ----
    k_gemm<128, 64, false><<<gemm_grid, 256, 0, stream>>>(x, W0, nullptr, nullptr, P, N);
    hipMemsetAsync(bn, 0, 1024, stream);
    k_agg128<<<agg_grid, 256, 0, stream>>>(P, rowptr, srcs, coefs, dinv, b0, F, bn, bn + 128, N);
    k_bnfin<<<1, 128, 0, stream>>>(bn, bn + 128, g0, be0, bn + 256, bn + 384, N);

    // ---- layer 1 ----
    k_gemm<128, 64, true><<<gemm_grid, 256, 0, stream>>>(F, W1, bn + 256, bn + 384, P, N);
    hipMemsetAsync(bn, 0, 1024, stream);
    k_agg128<<<agg_grid, 256, 0, stream>>>(P, rowptr, srcs, coefs, dinv, b1, F, bn, bn + 128, N);
    k_bnfin<<<1, 128, 0, stream>>>(bn, bn + 128, g1, be1, bn + 256, bn + 384, N);

    // ---- layer 2 ----
    k_gemm<40, 128, true><<<gemm_grid, 256, 0, stream>>>(F, W2, bn + 256, bn + 384, P, N);
    k_agg40<<<agg_grid, 256, 0, stream>>>(P, rowptr, srcs, coefs, dinv, b2, (float*)d_out, N);
}

// Round 3
// 849.825 us; speedup vs baseline: 1.8384x; 1.8384x over previous
//
#include <hip/hip_runtime.h>
#include <math.h>

// ---------------------------------------------------------------------------
// GCN 3-layer forward. Round 2: restore round-0 aggregation structure
// (sequential node chunk per wave, named-scalar 4-deep unroll => ~4 gathers
// in flight) with bf16-packed rows (256 B / 80 B per gather) and interleaved
// (src,coef) int2 edge stream. Block-LDS reduction before BN atomics.
// ---------------------------------------------------------------------------

__device__ __forceinline__ float2 bf2_unpack(unsigned u) {
    float2 r;
    r.x = __uint_as_float(u << 16);
    r.y = __uint_as_float(u & 0xffff0000u);
    return r;
}
__device__ __forceinline__ unsigned bf2_pack(float a, float b) {
    unsigned ua = __float_as_uint(a);
    unsigned ub = __float_as_uint(b);
    ua = (ua + 0x7fffu + ((ua >> 16) & 1u)) >> 16;
    ub = (ub + 0x7fffu + ((ub >> 16) & 1u)) >> 16;
    return ua | (ub << 16);
}

// ---------- edge-index dtype detection (int32 vs int64 layout) ----------
__global__ void k_detect(const unsigned* __restrict__ raw, int nsample, int* __restrict__ flag) {
    int i = blockIdx.x * blockDim.x + threadIdx.x;
    if (i < nsample) {
        if (raw[2 * i + 1] != 0u) atomicOr(flag, 1);
    }
}

__device__ __forceinline__ int edge_src(const unsigned* raw, int e, int E, int is64) {
    return is64 ? (int)raw[2 * (size_t)e] : (int)raw[e];
}
__device__ __forceinline__ int edge_dst(const unsigned* raw, int e, int E, int is64) {
    return is64 ? (int)raw[2 * ((size_t)E + e)] : (int)raw[(size_t)E + e];
}

// ---------- degree + per-dst edge counts ----------
__global__ void k_deg(const unsigned* __restrict__ raw, const float* __restrict__ ew,
                      float* __restrict__ degw, int* __restrict__ counts,
                      const int* __restrict__ flag, int E) {
    int e = blockIdx.x * blockDim.x + threadIdx.x;
    if (e >= E) return;
    int is64 = (*flag == 0);
    int d = edge_dst(raw, e, E, is64);
    atomicAdd(&degw[d], ew[e]);
    atomicAdd(&counts[d], 1);
}

// ---------- hierarchical exclusive scan over counts (N <= 131072) ----------
__global__ void k_scan_a(int* __restrict__ data, int* __restrict__ bsums, int N) {
    __shared__ int s[512];
    int tid = threadIdx.x;
    int i = blockIdx.x * 512 + tid;
    int v = (i < N) ? data[i] : 0;
    s[tid] = v;
    __syncthreads();
    for (int off = 1; off < 512; off <<= 1) {
        int t = (tid >= off) ? s[tid - off] : 0;
        __syncthreads();
        if (tid >= off) s[tid] += t;
        __syncthreads();
    }
    if (tid == 511) bsums[blockIdx.x] = s[511];
    if (i < N) data[i] = s[tid] - v;
}

__global__ void k_scan_b(int* __restrict__ bsums, int NB) {
    __shared__ int s[256];
    int tid = threadIdx.x;
    int v = (tid < NB) ? bsums[tid] : 0;
    s[tid] = v;
    __syncthreads();
    for (int off = 1; off < 256; off <<= 1) {
        int t = (tid >= off) ? s[tid - off] : 0;
        __syncthreads();
        if (tid >= off) s[tid] += t;
        __syncthreads();
    }
    if (tid < NB) bsums[tid] = s[tid] - v;
}

__global__ void k_scan_c(const int* __restrict__ data, const int* __restrict__ bsums,
                         int* __restrict__ rowptr, int* __restrict__ fill,
                         const float* __restrict__ degw, float* __restrict__ dinv,
                         int N, int E) {
    int i = blockIdx.x * 512 + threadIdx.x;
    if (i < N) {
        int v = data[i] + bsums[blockIdx.x];
        rowptr[i] = v;
        fill[i] = v;
        dinv[i] = rsqrtf(degw[i] + 1.0f);
    }
    if (blockIdx.x == 0 && threadIdx.x == 0) rowptr[N] = E;
}

// ---------- scatter edges into CSR slots: interleaved (src, coef) ----------
__global__ void k_scatter(const unsigned* __restrict__ raw, const float* __restrict__ ew,
                          const float* __restrict__ dinv, int* __restrict__ fill,
                          int2* __restrict__ ep, const int* __restrict__ flag, int E) {
    int e = blockIdx.x * blockDim.x + threadIdx.x;
    if (e >= E) return;
    int is64 = (*flag == 0);
    int s = edge_src(raw, e, E, is64);
    int d = edge_dst(raw, e, E, is64);
    float c = dinv[s] * ew[e] * dinv[d];
    int p = atomicAdd(&fill[d], 1);
    ep[p] = make_int2(s, __float_as_int(c));
}

// ---------- fp32 GEMM: Yp = pack_bf162( act(X)[N,128] @ W[128,DOUT] ) ----------
template <int DOUT, int KC, bool BN>
__global__ __launch_bounds__(256) void k_gemm(
    const float* __restrict__ X, const float* __restrict__ W,
    const float* __restrict__ scale, const float* __restrict__ shift,
    unsigned* __restrict__ Y, int N)
{
    constexpr int NCH = 128 / KC;
    constexpr int NDW = DOUT / 2;
    __shared__ __align__(16) float Wl[KC * DOUT];
    __shared__ __align__(16) float Xs[4][8 * 128];
    __shared__ float sc_l[128], sh_l[128];

    const int tid = threadIdx.x;
    const int wave = tid >> 6, lane = tid & 63;
    if (BN) {
        if (tid < 128) { sc_l[tid] = scale[tid]; sh_l[tid] = shift[tid]; }
    }
    __syncthreads();

    const int srow = lane >> 3;
    const int skk = (lane & 7) * 16;

    for (int base = blockIdx.x * 32; base < N; base += gridDim.x * 32) {
        {
            int r = base + wave * 8 + srow;
            float4 v[4];
            if (r < N) {
                const float4* p = (const float4*)(X + (size_t)r * 128 + skk);
                v[0] = p[0]; v[1] = p[1]; v[2] = p[2]; v[3] = p[3];
            } else {
                v[0] = v[1] = v[2] = v[3] = make_float4(0.f, 0.f, 0.f, 0.f);
            }
            if (BN) {
                float* vf = (float*)v;
#pragma unroll
                for (int j = 0; j < 16; j++)
                    vf[j] = fmaxf(vf[j] * sc_l[skk + j] + sh_l[skk + j], 0.f);
            }
            float4* q = (float4*)&Xs[wave][srow * 128 + skk];
            q[0] = v[0]; q[1] = v[1]; q[2] = v[2]; q[3] = v[3];
        }

        float acc0[8], acc1[8];
#pragma unroll
        for (int r = 0; r < 8; r++) { acc0[r] = 0.f; acc1[r] = 0.f; }

        for (int ch = 0; ch < NCH; ++ch) {
            __syncthreads();
            for (int idx = tid; idx < KC * DOUT / 4; idx += 256)
                ((float4*)Wl)[idx] = ((const float4*)(W + (size_t)ch * KC * DOUT))[idx];
            __syncthreads();

            for (int k = 0; k < KC; k += 4) {
                float4 a[8];
#pragma unroll
                for (int r = 0; r < 8; r++)
                    a[r] = *(const float4*)&Xs[wave][r * 128 + ch * KC + k];
#pragma unroll
                for (int kk = 0; kk < 4; kk++) {
                    float2 wv = make_float2(0.f, 0.f);
                    if (lane < NDW)
                        wv = *(const float2*)&Wl[(k + kk) * DOUT + 2 * lane];
#pragma unroll
                    for (int r = 0; r < 8; r++) {
                        float av = ((const float*)&a[r])[kk];
                        acc0[r] += av * wv.x;
                        acc1[r] += av * wv.y;
                    }
                }
            }
        }

#pragma unroll
        for (int r = 0; r < 8; r++) {
            int row = base + wave * 8 + r;
            if (row < N && lane < NDW)
                Y[(size_t)row * NDW + lane] = bf2_pack(acc0[r], acc1[r]);
        }
    }
}

// ---------- aggregation (128-wide, bf16 gather) + bias + BN partial sums ----------
// Block = 4 waves; wave owns 16 consecutive nodes; lane = packed dword column.
// Named-scalar 4-deep unroll keeps ~4 gathers in flight per wave.
__global__ __launch_bounds__(256) void k_agg128(
    const unsigned* __restrict__ xw, const int* __restrict__ rowptr,
    const int2* __restrict__ ep, const float* __restrict__ dinv,
    const float* __restrict__ bias, float* __restrict__ h,
    float* __restrict__ bn_sum, float* __restrict__ bn_sq, int N)
{
    __shared__ float redS[512], redQ[512];
    const int lane = threadIdx.x & 63;
    const int wave = threadIdx.x >> 6;
    const int base = blockIdx.x * 64 + wave * 16;
    const float b0 = bias[2 * lane], b1 = bias[2 * lane + 1];
    float s0 = 0.f, s1 = 0.f, q0 = 0.f, q1 = 0.f;

    const int nmax = (N - base < 16) ? (N - base) : 16;
    for (int n = 0; n < nmax; n++) {
        const int i = base + n;
        const int rs = rowptr[i], re = rowptr[i + 1];
        const float di = dinv[i];
        float2 sv = bf2_unpack(xw[(size_t)i * 64 + lane]);
        float acc0 = di * di * sv.x, acc1 = di * di * sv.y;
        int j = rs;
        for (; j + 4 <= re; j += 4) {
            int2 e0 = ep[j], e1 = ep[j + 1], e2 = ep[j + 2], e3 = ep[j + 3];
            unsigned v0 = xw[(size_t)e0.x * 64 + lane];
            unsigned v1 = xw[(size_t)e1.x * 64 + lane];
            unsigned v2 = xw[(size_t)e2.x * 64 + lane];
            unsigned v3 = xw[(size_t)e3.x * 64 + lane];
            float c0 = __int_as_float(e0.y), c1 = __int_as_float(e1.y);
            float c2 = __int_as_float(e2.y), c3 = __int_as_float(e3.y);
            float2 f0 = bf2_unpack(v0), f1 = bf2_unpack(v1);
            float2 f2 = bf2_unpack(v2), f3 = bf2_unpack(v3);
            acc0 += c0 * f0.x + c1 * f1.x + c2 * f2.x + c3 * f3.x;
            acc1 += c0 * f0.y + c1 * f1.y + c2 * f2.y + c3 * f3.y;
        }
        for (; j < re; j++) {
            int2 e = ep[j];
            float c = __int_as_float(e.y);
            float2 f = bf2_unpack(xw[(size_t)e.x * 64 + lane]);
            acc0 += c * f.x;
            acc1 += c * f.y;
        }
        acc0 += b0; acc1 += b1;
        *(float2*)&h[(size_t)i * 128 + 2 * lane] = make_float2(acc0, acc1);
        s0 += acc0; s1 += acc1; q0 += acc0 * acc0; q1 += acc1 * acc1;
    }

    // block-level reduction of BN partials, then 2 atomics per feature
    redS[wave * 128 + 2 * lane] = s0;
    redS[wave * 128 + 2 * lane + 1] = s1;
    redQ[wave * 128 + 2 * lane] = q0;
    redQ[wave * 128 + 2 * lane + 1] = q1;
    __syncthreads();
    if (threadIdx.x < 128) {
        int f = threadIdx.x;
        float ts = redS[f] + redS[128 + f] + redS[256 + f] + redS[384 + f];
        float tq = redQ[f] + redQ[128 + f] + redQ[256 + f] + redQ[384 + f];
        atomicAdd(&bn_sum[f], ts);
        atomicAdd(&bn_sq[f], tq);
    }
}

// ---------- BN finalize ----------
__global__ void k_bnfin(const float* __restrict__ bn_sum, const float* __restrict__ bn_sq,
                        const float* __restrict__ gamma, const float* __restrict__ beta,
                        float* __restrict__ scale, float* __restrict__ shift, int N) {
    int f = threadIdx.x;
    float inv = 1.0f / (float)N;
    float m = bn_sum[f] * inv;
    float v = bn_sq[f] * inv - m * m;
    float sc = gamma[f] * rsqrtf(v + 1e-5f);
    scale[f] = sc;
    shift[f] = beta[f] - m * sc;
}

// ---------- aggregation (40-wide, bf16 gather) + bias + log_softmax ----------
// Wave owns 16 consecutive nodes, processed 2 at a time (one per half-wave);
// within a half, lanes 0..19 hold the 20 packed dword columns.
__global__ __launch_bounds__(256) void k_agg40(
    const unsigned* __restrict__ xw, const int* __restrict__ rowptr,
    const int2* __restrict__ ep, const float* __restrict__ dinv,
    const float* __restrict__ bias, float* __restrict__ out, int N)
{
    const int lane = threadIdx.x & 63;
    const int wave = threadIdx.x >> 6;
    const int half = lane >> 5;
    const int col = lane & 31;
    const bool act = col < 20;
    const int base = blockIdx.x * 64 + wave * 16;
    if (base >= N) return;
    const int cc = act ? col : 0;
    const float b0 = act ? bias[2 * col] : 0.f;
    const float b1 = act ? bias[2 * col + 1] : 0.f;

    for (int n = 0; n < 16; n += 2) {
        const int i = base + n + half;
        const bool valid = i < N;
        const int ic = valid ? i : 0;
        const int rs = rowptr[ic];
        int re = rowptr[ic + 1];
        re = valid ? re : rs;
        const float di = dinv[ic];
        float2 sv = bf2_unpack(xw[(size_t)ic * 20 + cc]);
        float acc0 = di * di * sv.x, acc1 = di * di * sv.y;
        int j = rs;
        for (; j + 4 <= re; j += 4) {
            int2 e0 = ep[j], e1 = ep[j + 1], e2 = ep[j + 2], e3 = ep[j + 3];
            unsigned v0 = xw[(size_t)e0.x * 20 + cc];
            unsigned v1 = xw[(size_t)e1.x * 20 + cc];
            unsigned v2 = xw[(size_t)e2.x * 20 + cc];
            unsigned v3 = xw[(size_t)e3.x * 20 + cc];
            float c0 = __int_as_float(e0.y), c1 = __int_as_float(e1.y);
            float c2 = __int_as_float(e2.y), c3 = __int_as_float(e3.y);
            float2 f0 = bf2_unpack(v0), f1 = bf2_unpack(v1);
            float2 f2 = bf2_unpack(v2), f3 = bf2_unpack(v3);
            acc0 += c0 * f0.x + c1 * f1.x + c2 * f2.x + c3 * f3.x;
            acc1 += c0 * f0.y + c1 * f1.y + c2 * f2.y + c3 * f3.y;
        }
        for (; j < re; j++) {
            int2 e = ep[j];
            float c = __int_as_float(e.y);
            float2 f = bf2_unpack(xw[(size_t)e.x * 20 + cc]);
            acc0 += c * f.x;
            acc1 += c * f.y;
        }
        acc0 += b0; acc1 += b1;

        // log-softmax over the 20 active lanes of this half (offsets <= 16
        // never cross the 32-lane half boundary)
        float m = act ? fmaxf(acc0, acc1) : -1e30f;
#pragma unroll
        for (int off = 16; off; off >>= 1) m = fmaxf(m, __shfl_xor(m, off));
        float ex = act ? (expf(acc0 - m) + expf(acc1 - m)) : 0.f;
#pragma unroll
        for (int off = 16; off; off >>= 1) ex += __shfl_xor(ex, off);
        float ls = logf(ex);
        if (act && valid)
            *(float2*)&out[(size_t)i * 40 + 2 * col] = make_float2(acc0 - m - ls, acc1 - m - ls);
    }
}

// ---------------------------------------------------------------------------
extern "C" void kernel_launch(void* const* d_in, const int* in_sizes, int n_in,
                              void* d_out, int out_size, void* d_ws, size_t ws_size,
                              hipStream_t stream) {
    const float* x   = (const float*)d_in[0];
    const unsigned* ei = (const unsigned*)d_in[1];
    const float* ew  = (const float*)d_in[2];
    const float* W0  = (const float*)d_in[3];
    const float* b0  = (const float*)d_in[4];
    const float* g0  = (const float*)d_in[5];
    const float* be0 = (const float*)d_in[6];
    const float* W1  = (const float*)d_in[7];
    const float* b1  = (const float*)d_in[8];
    const float* g1  = (const float*)d_in[9];
    const float* be1 = (const float*)d_in[10];
    const float* W2  = (const float*)d_in[11];
    const float* b2  = (const float*)d_in[12];

    const int N = in_sizes[0] / 128;
    const int E = in_sizes[2];
    if (N <= 0 || E <= 0) return;

    char* ws = (char*)d_ws;
    size_t off = 0;
    auto carve = [&](size_t bytes) {
        char* p = ws + off;
        off += (bytes + 511) & ~((size_t)511);
        return p;
    };
    float*    F      = (float*)carve((size_t)N * 128 * 4);    // fp32 h buffer
    unsigned* P      = (unsigned*)carve((size_t)N * 64 * 4);  // packed bf162 xw
    int2*     ep     = (int2*)carve((size_t)E * 8);           // (src, coef) pairs
    int*      rowptr = (int*)carve((size_t)(N + 1) * 4);
    int*      fill   = (int*)carve((size_t)N * 4);
    int*      counts = (int*)carve((size_t)N * 4);
    float*    degw   = (float*)carve((size_t)N * 4);
    float*    dinv   = (float*)carve((size_t)N * 4);
    int*      bsums  = (int*)carve(1024 * 4);
    float*    bn     = (float*)carve(512 * 4);
    int*      flag   = (int*)carve(64);

    hipMemsetAsync(degw, 0, (size_t)N * 4, stream);
    hipMemsetAsync(counts, 0, (size_t)N * 4, stream);
    hipMemsetAsync(flag, 0, 4, stream);

    int nsample = E < 4096 ? E : 4096;
    k_detect<<<(nsample + 255) / 256, 256, 0, stream>>>(ei, nsample, flag);
    k_deg<<<(E + 255) / 256, 256, 0, stream>>>(ei, ew, degw, counts, flag, E);
    const int NB = (N + 511) / 512;
    k_scan_a<<<NB, 512, 0, stream>>>(counts, bsums, N);
    k_scan_b<<<1, 256, 0, stream>>>(bsums, NB);
    k_scan_c<<<NB, 512, 0, stream>>>(counts, bsums, rowptr, fill, degw, dinv, N, E);
    k_scatter<<<(E + 255) / 256, 256, 0, stream>>>(ei, ew, dinv, fill, ep, flag, E);

    const int gemm_grid = 768;
    const int agg_grid = (N + 63) / 64;

    // ---- layer 0 ----
    k_gemm<128, 64, false><<<gemm_grid, 256, 0, stream>>>(x, W0, nullptr, nullptr, P, N);
    hipMemsetAsync(bn, 0, 1024, stream);
    k_agg128<<<agg_grid, 256, 0, stream>>>(P, rowptr, ep, dinv, b0, F, bn, bn + 128, N);
    k_bnfin<<<1, 128, 0, stream>>>(bn, bn + 128, g0, be0, bn + 256, bn + 384, N);

    // ---- layer 1 ----
    k_gemm<128, 64, true><<<gemm_grid, 256, 0, stream>>>(F, W1, bn + 256, bn + 384, P, N);
    hipMemsetAsync(bn, 0, 1024, stream);
    k_agg128<<<agg_grid, 256, 0, stream>>>(P, rowptr, ep, dinv, b1, F, bn, bn + 128, N);
    k_bnfin<<<1, 128, 0, stream>>>(bn, bn + 128, g1, be1, bn + 256, bn + 384, N);

    // ---- layer 2 ----
    k_gemm<40, 128, true><<<gemm_grid, 256, 0, stream>>>(F, W2, bn + 256, bn + 384, P, N);
    k_agg40<<<agg_grid, 256, 0, stream>>>(P, rowptr, ep, dinv, b2, (float*)d_out, N);
}

// Round 4
// 775.527 us; speedup vs baseline: 2.0145x; 1.0958x over previous
//
#include <hip/hip_runtime.h>
#include <math.h>

// ---------------------------------------------------------------------------
// GCN 3-layer forward. Round 3: atomic-diet preprocessing.
//  - k_count: counts only (1.6M atomics, was 3.2M in k_deg)
//  - degw via atomic-free segmented sum AFTER scatter (k_dinv)
//  - row pre-scaling: GEMM writes xw'[r] = dinv[r]*(X@W)[r] packed bf162, so
//    edge payload is raw (src, ew) and h[d] = dinv[d]*(sum + self) + b.
// Aggregation keeps the round-2 structure (wave-owns-16-nodes, named-scalar
// 4-deep unroll).
// ---------------------------------------------------------------------------

__device__ __forceinline__ float2 bf2_unpack(unsigned u) {
    float2 r;
    r.x = __uint_as_float(u << 16);
    r.y = __uint_as_float(u & 0xffff0000u);
    return r;
}
__device__ __forceinline__ unsigned bf2_pack(float a, float b) {
    unsigned ua = __float_as_uint(a);
    unsigned ub = __float_as_uint(b);
    ua = (ua + 0x7fffu + ((ua >> 16) & 1u)) >> 16;
    ub = (ub + 0x7fffu + ((ub >> 16) & 1u)) >> 16;
    return ua | (ub << 16);
}

// ---------- edge-index dtype detection (int32 vs int64 layout) ----------
__global__ void k_detect(const unsigned* __restrict__ raw, int nsample, int* __restrict__ flag) {
    int i = blockIdx.x * blockDim.x + threadIdx.x;
    if (i < nsample) {
        if (raw[2 * i + 1] != 0u) atomicOr(flag, 1);
    }
}

__device__ __forceinline__ int edge_src(const unsigned* raw, int e, int E, int is64) {
    return is64 ? (int)raw[2 * (size_t)e] : (int)raw[e];
}
__device__ __forceinline__ int edge_dst(const unsigned* raw, int e, int E, int is64) {
    return is64 ? (int)raw[2 * ((size_t)E + e)] : (int)raw[(size_t)E + e];
}

// ---------- per-dst edge counts (counts only; degw comes later) ----------
__global__ void k_count(const unsigned* __restrict__ raw, int* __restrict__ counts,
                        const int* __restrict__ flag, int E) {
    int e = blockIdx.x * blockDim.x + threadIdx.x;
    if (e >= E) return;
    int is64 = (*flag == 0);
    int d = edge_dst(raw, e, E, is64);
    atomicAdd(&counts[d], 1);
}

// ---------- hierarchical exclusive scan over counts (N <= 131072) ----------
__global__ void k_scan_a(int* __restrict__ data, int* __restrict__ bsums, int N) {
    __shared__ int s[512];
    int tid = threadIdx.x;
    int i = blockIdx.x * 512 + tid;
    int v = (i < N) ? data[i] : 0;
    s[tid] = v;
    __syncthreads();
    for (int off = 1; off < 512; off <<= 1) {
        int t = (tid >= off) ? s[tid - off] : 0;
        __syncthreads();
        if (tid >= off) s[tid] += t;
        __syncthreads();
    }
    if (tid == 511) bsums[blockIdx.x] = s[511];
    if (i < N) data[i] = s[tid] - v;
}

__global__ void k_scan_b(int* __restrict__ bsums, int NB) {
    __shared__ int s[256];
    int tid = threadIdx.x;
    int v = (tid < NB) ? bsums[tid] : 0;
    s[tid] = v;
    __syncthreads();
    for (int off = 1; off < 256; off <<= 1) {
        int t = (tid >= off) ? s[tid - off] : 0;
        __syncthreads();
        if (tid >= off) s[tid] += t;
        __syncthreads();
    }
    if (tid < NB) bsums[tid] = s[tid] - v;
}

__global__ void k_scan_c(const int* __restrict__ data, const int* __restrict__ bsums,
                         int* __restrict__ rowptr, int* __restrict__ fill, int N, int E) {
    int i = blockIdx.x * 512 + threadIdx.x;
    if (i < N) {
        int v = data[i] + bsums[blockIdx.x];
        rowptr[i] = v;
        fill[i] = v;
    }
    if (blockIdx.x == 0 && threadIdx.x == 0) rowptr[N] = E;
}

// ---------- scatter edges into CSR slots: payload (src, raw ew) ----------
__global__ void k_scatter(const unsigned* __restrict__ raw, const float* __restrict__ ew,
                          int* __restrict__ fill, int2* __restrict__ ep,
                          const int* __restrict__ flag, int E) {
    int e = blockIdx.x * blockDim.x + threadIdx.x;
    if (e >= E) return;
    int is64 = (*flag == 0);
    int s = edge_src(raw, e, E, is64);
    int d = edge_dst(raw, e, E, is64);
    int p = atomicAdd(&fill[d], 1);
    ep[p] = make_int2(s, __float_as_int(ew[e]));
}

// ---------- atomic-free degree: segmented sum of ew over CSR rows ----------
__global__ void k_dinv(const int* __restrict__ rowptr, const int2* __restrict__ ep,
                       float* __restrict__ dinv, int N) {
    int i = blockIdx.x * blockDim.x + threadIdx.x;
    if (i >= N) return;
    int rs = rowptr[i], re = rowptr[i + 1];
    float s = 0.f;
    for (int j = rs; j < re; j++) s += __int_as_float(ep[j].y);
    dinv[i] = rsqrtf(s + 1.0f);  // deg includes self-loop weight 1.0
}

// ---------- fp32 GEMM: Yp = pack_bf162( dinv[r] * act(X)[N,128] @ W ) ----------
template <int DOUT, int KC, bool BN>
__global__ __launch_bounds__(256) void k_gemm(
    const float* __restrict__ X, const float* __restrict__ W,
    const float* __restrict__ scale, const float* __restrict__ shift,
    const float* __restrict__ dscale, unsigned* __restrict__ Y, int N)
{
    constexpr int NCH = 128 / KC;
    constexpr int NDW = DOUT / 2;
    __shared__ __align__(16) float Wl[KC * DOUT];
    __shared__ __align__(16) float Xs[4][8 * 128];
    __shared__ float sc_l[128], sh_l[128];

    const int tid = threadIdx.x;
    const int wave = tid >> 6, lane = tid & 63;
    if (BN) {
        if (tid < 128) { sc_l[tid] = scale[tid]; sh_l[tid] = shift[tid]; }
    }
    __syncthreads();

    const int srow = lane >> 3;
    const int skk = (lane & 7) * 16;

    for (int base = blockIdx.x * 32; base < N; base += gridDim.x * 32) {
        {
            int r = base + wave * 8 + srow;
            float4 v[4];
            if (r < N) {
                const float4* p = (const float4*)(X + (size_t)r * 128 + skk);
                v[0] = p[0]; v[1] = p[1]; v[2] = p[2]; v[3] = p[3];
            } else {
                v[0] = v[1] = v[2] = v[3] = make_float4(0.f, 0.f, 0.f, 0.f);
            }
            if (BN) {
                float* vf = (float*)v;
#pragma unroll
                for (int j = 0; j < 16; j++)
                    vf[j] = fmaxf(vf[j] * sc_l[skk + j] + sh_l[skk + j], 0.f);
            }
            float4* q = (float4*)&Xs[wave][srow * 128 + skk];
            q[0] = v[0]; q[1] = v[1]; q[2] = v[2]; q[3] = v[3];
        }

        float acc0[8], acc1[8];
#pragma unroll
        for (int r = 0; r < 8; r++) { acc0[r] = 0.f; acc1[r] = 0.f; }

        for (int ch = 0; ch < NCH; ++ch) {
            __syncthreads();
            for (int idx = tid; idx < KC * DOUT / 4; idx += 256)
                ((float4*)Wl)[idx] = ((const float4*)(W + (size_t)ch * KC * DOUT))[idx];
            __syncthreads();

            for (int k = 0; k < KC; k += 4) {
                float4 a[8];
#pragma unroll
                for (int r = 0; r < 8; r++)
                    a[r] = *(const float4*)&Xs[wave][r * 128 + ch * KC + k];
#pragma unroll
                for (int kk = 0; kk < 4; kk++) {
                    float2 wv = make_float2(0.f, 0.f);
                    if (lane < NDW)
                        wv = *(const float2*)&Wl[(k + kk) * DOUT + 2 * lane];
#pragma unroll
                    for (int r = 0; r < 8; r++) {
                        float av = ((const float*)&a[r])[kk];
                        acc0[r] += av * wv.x;
                        acc1[r] += av * wv.y;
                    }
                }
            }
        }

#pragma unroll
        for (int r = 0; r < 8; r++) {
            int row = base + wave * 8 + r;
            if (row < N && lane < NDW) {
                float rs = dscale[row];
                Y[(size_t)row * NDW + lane] = bf2_pack(acc0[r] * rs, acc1[r] * rs);
            }
        }
    }
}

// ---------- aggregation (128-wide, bf16 gather) + bias + BN partial sums ----------
// h[i] = dinv[i]*(sum_e ew*xw'[src] + xw'[i]) + b
__global__ __launch_bounds__(256) void k_agg128(
    const unsigned* __restrict__ xw, const int* __restrict__ rowptr,
    const int2* __restrict__ ep, const float* __restrict__ dinv,
    const float* __restrict__ bias, float* __restrict__ h,
    float* __restrict__ bn_sum, float* __restrict__ bn_sq, int N)
{
    __shared__ float redS[512], redQ[512];
    const int lane = threadIdx.x & 63;
    const int wave = threadIdx.x >> 6;
    const int base = blockIdx.x * 64 + wave * 16;
    const float b0 = bias[2 * lane], b1 = bias[2 * lane + 1];
    float s0 = 0.f, s1 = 0.f, q0 = 0.f, q1 = 0.f;

    const int nmax = (N - base < 16) ? (N - base) : 16;
    for (int n = 0; n < nmax; n++) {
        const int i = base + n;
        const int rs = rowptr[i], re = rowptr[i + 1];
        const float di = dinv[i];
        float2 sv = bf2_unpack(xw[(size_t)i * 64 + lane]);
        float acc0 = sv.x, acc1 = sv.y;  // self-loop message xw'[i]
        int j = rs;
        for (; j + 4 <= re; j += 4) {
            int2 e0 = ep[j], e1 = ep[j + 1], e2 = ep[j + 2], e3 = ep[j + 3];
            unsigned v0 = xw[(size_t)e0.x * 64 + lane];
            unsigned v1 = xw[(size_t)e1.x * 64 + lane];
            unsigned v2 = xw[(size_t)e2.x * 64 + lane];
            unsigned v3 = xw[(size_t)e3.x * 64 + lane];
            float c0 = __int_as_float(e0.y), c1 = __int_as_float(e1.y);
            float c2 = __int_as_float(e2.y), c3 = __int_as_float(e3.y);
            float2 f0 = bf2_unpack(v0), f1 = bf2_unpack(v1);
            float2 f2 = bf2_unpack(v2), f3 = bf2_unpack(v3);
            acc0 += c0 * f0.x + c1 * f1.x + c2 * f2.x + c3 * f3.x;
            acc1 += c0 * f0.y + c1 * f1.y + c2 * f2.y + c3 * f3.y;
        }
        for (; j < re; j++) {
            int2 e = ep[j];
            float c = __int_as_float(e.y);
            float2 f = bf2_unpack(xw[(size_t)e.x * 64 + lane]);
            acc0 += c * f.x;
            acc1 += c * f.y;
        }
        acc0 = acc0 * di + b0;
        acc1 = acc1 * di + b1;
        *(float2*)&h[(size_t)i * 128 + 2 * lane] = make_float2(acc0, acc1);
        s0 += acc0; s1 += acc1; q0 += acc0 * acc0; q1 += acc1 * acc1;
    }

    redS[wave * 128 + 2 * lane] = s0;
    redS[wave * 128 + 2 * lane + 1] = s1;
    redQ[wave * 128 + 2 * lane] = q0;
    redQ[wave * 128 + 2 * lane + 1] = q1;
    __syncthreads();
    if (threadIdx.x < 128) {
        int f = threadIdx.x;
        float ts = redS[f] + redS[128 + f] + redS[256 + f] + redS[384 + f];
        float tq = redQ[f] + redQ[128 + f] + redQ[256 + f] + redQ[384 + f];
        atomicAdd(&bn_sum[f], ts);
        atomicAdd(&bn_sq[f], tq);
    }
}

// ---------- BN finalize ----------
__global__ void k_bnfin(const float* __restrict__ bn_sum, const float* __restrict__ bn_sq,
                        const float* __restrict__ gamma, const float* __restrict__ beta,
                        float* __restrict__ scale, float* __restrict__ shift, int N) {
    int f = threadIdx.x;
    float inv = 1.0f / (float)N;
    float m = bn_sum[f] * inv;
    float v = bn_sq[f] * inv - m * m;
    float sc = gamma[f] * rsqrtf(v + 1e-5f);
    scale[f] = sc;
    shift[f] = beta[f] - m * sc;
}

// ---------- aggregation (40-wide, bf16 gather) + bias + log_softmax ----------
__global__ __launch_bounds__(256) void k_agg40(
    const unsigned* __restrict__ xw, const int* __restrict__ rowptr,
    const int2* __restrict__ ep, const float* __restrict__ dinv,
    const float* __restrict__ bias, float* __restrict__ out, int N)
{
    const int lane = threadIdx.x & 63;
    const int wave = threadIdx.x >> 6;
    const int half = lane >> 5;
    const int col = lane & 31;
    const bool act = col < 20;
    const int base = blockIdx.x * 64 + wave * 16;
    if (base >= N) return;
    const int cc = act ? col : 0;
    const float b0 = act ? bias[2 * col] : 0.f;
    const float b1 = act ? bias[2 * col + 1] : 0.f;

    for (int n = 0; n < 16; n += 2) {
        const int i = base + n + half;
        const bool valid = i < N;
        const int ic = valid ? i : 0;
        const int rs = rowptr[ic];
        int re = rowptr[ic + 1];
        re = valid ? re : rs;
        const float di = dinv[ic];
        float2 sv = bf2_unpack(xw[(size_t)ic * 20 + cc]);
        float acc0 = sv.x, acc1 = sv.y;  // self-loop message
        int j = rs;
        for (; j + 4 <= re; j += 4) {
            int2 e0 = ep[j], e1 = ep[j + 1], e2 = ep[j + 2], e3 = ep[j + 3];
            unsigned v0 = xw[(size_t)e0.x * 20 + cc];
            unsigned v1 = xw[(size_t)e1.x * 20 + cc];
            unsigned v2 = xw[(size_t)e2.x * 20 + cc];
            unsigned v3 = xw[(size_t)e3.x * 20 + cc];
            float c0 = __int_as_float(e0.y), c1 = __int_as_float(e1.y);
            float c2 = __int_as_float(e2.y), c3 = __int_as_float(e3.y);
            float2 f0 = bf2_unpack(v0), f1 = bf2_unpack(v1);
            float2 f2 = bf2_unpack(v2), f3 = bf2_unpack(v3);
            acc0 += c0 * f0.x + c1 * f1.x + c2 * f2.x + c3 * f3.x;
            acc1 += c0 * f0.y + c1 * f1.y + c2 * f2.y + c3 * f3.y;
        }
        for (; j < re; j++) {
            int2 e = ep[j];
            float c = __int_as_float(e.y);
            float2 f = bf2_unpack(xw[(size_t)e.x * 20 + cc]);
            acc0 += c * f.x;
            acc1 += c * f.y;
        }
        acc0 = acc0 * di + b0;
        acc1 = acc1 * di + b1;

        float m = act ? fmaxf(acc0, acc1) : -1e30f;
#pragma unroll
        for (int off = 16; off; off >>= 1) m = fmaxf(m, __shfl_xor(m, off));
        float ex = act ? (expf(acc0 - m) + expf(acc1 - m)) : 0.f;
#pragma unroll
        for (int off = 16; off; off >>= 1) ex += __shfl_xor(ex, off);
        float ls = logf(ex);
        if (act && valid)
            *(float2*)&out[(size_t)i * 40 + 2 * col] = make_float2(acc0 - m - ls, acc1 - m - ls);
    }
}

// ---------------------------------------------------------------------------
extern "C" void kernel_launch(void* const* d_in, const int* in_sizes, int n_in,
                              void* d_out, int out_size, void* d_ws, size_t ws_size,
                              hipStream_t stream) {
    const float* x   = (const float*)d_in[0];
    const unsigned* ei = (const unsigned*)d_in[1];
    const float* ew  = (const float*)d_in[2];
    const float* W0  = (const float*)d_in[3];
    const float* b0  = (const float*)d_in[4];
    const float* g0  = (const float*)d_in[5];
    const float* be0 = (const float*)d_in[6];
    const float* W1  = (const float*)d_in[7];
    const float* b1  = (const float*)d_in[8];
    const float* g1  = (const float*)d_in[9];
    const float* be1 = (const float*)d_in[10];
    const float* W2  = (const float*)d_in[11];
    const float* b2  = (const float*)d_in[12];

    const int N = in_sizes[0] / 128;
    const int E = in_sizes[2];
    if (N <= 0 || E <= 0) return;

    char* ws = (char*)d_ws;
    size_t off = 0;
    auto carve = [&](size_t bytes) {
        char* p = ws + off;
        off += (bytes + 511) & ~((size_t)511);
        return p;
    };
    float*    F      = (float*)carve((size_t)N * 128 * 4);    // fp32 h buffer
    unsigned* P      = (unsigned*)carve((size_t)N * 64 * 4);  // packed bf162 xw'
    int2*     ep     = (int2*)carve((size_t)E * 8);           // (src, ew) pairs
    int*      rowptr = (int*)carve((size_t)(N + 1) * 4);
    int*      fill   = (int*)carve((size_t)N * 4);
    int*      counts = (int*)carve((size_t)N * 4);
    float*    dinv   = (float*)carve((size_t)N * 4);
    int*      bsums  = (int*)carve(1024 * 4);
    float*    bn     = (float*)carve(512 * 4);
    int*      flag   = (int*)carve(64);

    hipMemsetAsync(counts, 0, (size_t)N * 4, stream);
    hipMemsetAsync(flag, 0, 4, stream);

    int nsample = E < 4096 ? E : 4096;
    k_detect<<<(nsample + 255) / 256, 256, 0, stream>>>(ei, nsample, flag);
    k_count<<<(E + 255) / 256, 256, 0, stream>>>(ei, counts, flag, E);
    const int NB = (N + 511) / 512;
    k_scan_a<<<NB, 512, 0, stream>>>(counts, bsums, N);
    k_scan_b<<<1, 256, 0, stream>>>(bsums, NB);
    k_scan_c<<<NB, 512, 0, stream>>>(counts, bsums, rowptr, fill, N, E);
    k_scatter<<<(E + 255) / 256, 256, 0, stream>>>(ei, ew, fill, ep, flag, E);
    k_dinv<<<(N + 255) / 256, 256, 0, stream>>>(rowptr, ep, dinv, N);

    const int gemm_grid = 768;
    const int agg_grid = (N + 63) / 64;

    // ---- layer 0 ----
    k_gemm<128, 64, false><<<gemm_grid, 256, 0, stream>>>(x, W0, nullptr, nullptr, dinv, P, N);
    hipMemsetAsync(bn, 0, 1024, stream);
    k_agg128<<<agg_grid, 256, 0, stream>>>(P, rowptr, ep, dinv, b0, F, bn, bn + 128, N);
    k_bnfin<<<1, 128, 0, stream>>>(bn, bn + 128, g0, be0, bn + 256, bn + 384, N);

    // ---- layer 1 ----
    k_gemm<128, 64, true><<<gemm_grid, 256, 0, stream>>>(F, W1, bn + 256, bn + 384, dinv, P, N);
    hipMemsetAsync(bn, 0, 1024, stream);
    k_agg128<<<agg_grid, 256, 0, stream>>>(P, rowptr, ep, dinv, b1, F, bn, bn + 128, N);
    k_bnfin<<<1, 128, 0, stream>>>(bn, bn + 128, g1, be1, bn + 256, bn + 384, N);

    // ---- layer 2 ----
    k_gemm<40, 128, true><<<gemm_grid, 256, 0, stream>>>(F, W2, bn + 256, bn + 384, dinv, P, N);
    k_agg40<<<agg_grid, 256, 0, stream>>>(P, rowptr, ep, dinv, b2, (float*)d_out, N);
}